// Round 3
// baseline (632.491 us; speedup 1.0000x reference)
//
#include <hip/hip_runtime.h>

// Sggnn_23218593202512 — round 16: occupancy fix. R13-R15 all sat at
// OccupancyPercent ~22% = 1 block/CU: the 256^2/8-wave design needs
// acc[8][4] = 128 AGPR + ~108 VGPR = 236 regs/wave vs the 512-reg unified
// pool -> 2 waves/SIMD -> no cross-block overlap, so every staging stall
// was exposed (which is why R14 dbuf and R15 counted-vmcnt were both ~null,
// matching m99-m141). Fix per the m97/m114 record (912 TF at ~3 blocks/CU
// with a plain 2-barrier loop): 128^2 tile, 256 thr / 4 waves, acc[4][4]
// (64 AGPR, ~164 regs/wave -> 3 waves/SIMD), single-buffered 32 KiB LDS
// (3x32=96 <= 160 KiB) -> ~3 blocks/CU implicit MFMA/VALU/VMEM overlap.
// Simple __syncthreads schedule; swizzle unchanged (conflicts 0).
// gemm_aff / prep / wtrans / wconv / finout byte-identical to R15.

typedef __bf16 bf16;
typedef __attribute__((ext_vector_type(8))) __bf16 bf16x8;
typedef __attribute__((ext_vector_type(4))) float f32x4;

#define EPSV 1e-5f

__device__ __forceinline__ void async_load16(const bf16* g, bf16* l) {
    __builtin_amdgcn_global_load_lds(
        (const __attribute__((address_space(1))) void*)g,
        (__attribute__((address_space(3))) void*)l, 16, 0, 0);
}

__global__ __launch_bounds__(256) void prep_kernel(
    const float* __restrict__ g, const float* __restrict__ b,
    const float* __restrict__ m, const float* __restrict__ v,
    const float* __restrict__ bias, float* __restrict__ scale,
    float* __restrict__ offset, int n)
{
    int i = blockIdx.x * 256 + threadIdx.x;
    if (i >= n) return;
    float s = g[i] / sqrtf(v[i] + EPSV);
    float o = b[i] - m[i] * s;
    if (bias) o += bias[i] * s;
    scale[i] = s;
    offset[i] = o;
}

__global__ __launch_bounds__(256) void wtrans_kernel(
    const float* __restrict__ in, bf16* __restrict__ out, int K, int N)
{
    int k = blockIdx.x * 256 + threadIdx.x;
    int n = blockIdx.y;
    out[(size_t)n * K + k] = (bf16)in[(size_t)k * N + n];
}

// wT[g2*256+g1] = bf16(w[g1][g2] + scl_b); only g-tiles ta<=tb computed,
// mirror otherwise (w symmetric). [R11/R12-verified]
__global__ __launch_bounds__(256) void wconv_kernel(
    const float* __restrict__ w_acc, const float* __restrict__ sclb,
    bf16* __restrict__ wT)
{
    int tid = blockIdx.x * 256 + threadIdx.x;
    int g2 = tid >> 8, g1 = tid & 255;
    int idx = ((g1 >> 4) <= (g2 >> 4)) ? (g1 * 256 + g2) : (g2 * 256 + g1);
    wT[tid] = (bf16)(w_acc[idx] + sclb[0]);
}

__global__ __launch_bounds__(256) void finout_kernel(
    const float* __restrict__ acc, const float* __restrict__ clsb,
    float* __restrict__ out)
{
    int i = blockIdx.x * 256 + threadIdx.x;
    out[i] = acc[i] + clsb[0];
}

// ---------- gemm128 (R16: m97-regime worker gemm) -------------------------
// C_z[M,N] = epi(A_z[M,K] @ BT_z[N,K]^T). 128x128 block, 256 thr = 4 waves
// (2 row x 2 col), wave 64x64 (acc[4][4]), BK=64, XOR-swizzled LDS,
// single-buffered 32 KiB -> ~3 blocks/CU (cross-block latency hiding).
// Per K-step: stage A+B -> __syncthreads -> ds_read + 32 MFMA/wave ->
// __syncthreads. Other resident blocks cover the staging stalls (m114).
// pair mode (PAIR): A[r][k]=(X[gr>>8][k]-Y[gr&255][k])^2*ps+po,
//   gr=rowOff+row0+r (not batched).
// fuse (fuseW!=0): rs += lrelu(bn(val))*fuseW[col] ->
//   atomicAdd facc[z*faccStride + global row].
template<bool PAIR>
__global__ __launch_bounds__(256) void gemm128(
    const bf16* __restrict__ A,
    const float* __restrict__ pairX, const float* __restrict__ pairY,
    const float* __restrict__ ps, const float* __restrict__ po,
    const bf16* __restrict__ BT,
    bf16* __restrict__ C,
    int K, int N, int rowOff,
    long long batchA, long long batchB, long long batchC,
    const float* __restrict__ scale, const float* __restrict__ offset,
    int lrelu,
    const float* __restrict__ fuseW, float* __restrict__ facc,
    long long faccStride)
{
    __shared__ bf16 As[128 * 64];   // 16 KiB
    __shared__ bf16 Bs[128 * 64];   // 16 KiB
    const int tid  = threadIdx.x;
    const int lane = tid & 63;
    const int wave = tid >> 6;
    const int wrow = wave >> 1, wcol = wave & 1;
    const int row0 = blockIdx.y * 128;
    const int col0 = blockIdx.x * 128;
    const int q = lane >> 4, l16 = lane & 15;
    const int z = blockIdx.z;

    const bf16* Ap = A + (size_t)z * (size_t)batchA;
    const bf16* Bp = BT + (size_t)z * (size_t)batchB;

    f32x4 acc[4][4];
#pragma unroll
    for (int mi = 0; mi < 4; ++mi)
#pragma unroll
        for (int ni = 0; ni < 4; ++ni)
#pragma unroll
            for (int e = 0; e < 4; ++e) acc[mi][ni][e] = 0.f;

    for (int kk = 0; kk < K; kk += 64) {
        // stage A (128 rows x 64 cols): 1024 16B-chunks, 4 per thread
        if constexpr (PAIR) {
#pragma unroll
            for (int t = 0; t < 4; ++t) {
                int c = tid + t * 256;      // 1024 tasks: r=c>>3, chunk=c&7
                int r = c >> 3, ch = c & 7;
                int gr = rowOff + row0 + r;
                const float* xp = pairX + (size_t)(gr >> 8) * K + kk + ch * 8;
                const float* yp = pairY + (size_t)(gr & 255) * K + kk + ch * 8;
                f32x4 x0 = *(const f32x4*)xp, x1 = *(const f32x4*)(xp + 4);
                f32x4 y0 = *(const f32x4*)yp, y1 = *(const f32x4*)(yp + 4);
                f32x4 sa = *(const f32x4*)(ps + kk + ch * 8);
                f32x4 sb = *(const f32x4*)(ps + kk + ch * 8 + 4);
                f32x4 oa = *(const f32x4*)(po + kk + ch * 8);
                f32x4 ob = *(const f32x4*)(po + kk + ch * 8 + 4);
                bf16x8 dv;
#pragma unroll
                for (int j = 0; j < 4; ++j) {
                    float d0 = x0[j] - y0[j];
                    float d1 = x1[j] - y1[j];
                    dv[j]     = (bf16)(d0 * d0 * sa[j] + oa[j]);
                    dv[j + 4] = (bf16)(d1 * d1 * sb[j] + ob[j]);
                }
                *(bf16x8*)&As[r * 64 + ((ch ^ (r & 7)) * 8)] = dv;
            }
        } else {
#pragma unroll
            for (int t = 0; t < 4; ++t) {
                int idx = t * 256 + tid;
                int r = idx >> 3, sch = idx & 7;
                int gch = sch ^ (r & 7);
                async_load16(Ap + (size_t)(row0 + r) * K + kk + gch * 8,
                             &As[idx * 8]);
            }
        }
        // stage B (128 rows x 64 cols)
#pragma unroll
        for (int t = 0; t < 4; ++t) {
            int idx = t * 256 + tid;
            int r = idx >> 3, sch = idx & 7;
            int gch = sch ^ (r & 7);
            async_load16(Bp + (size_t)(col0 + r) * K + kk + gch * 8,
                         &Bs[idx * 8]);
        }
        __syncthreads();

#pragma unroll
        for (int s = 0; s < 2; ++s) {
            bf16x8 af[4], bfr[4];
#pragma unroll
            for (int mi = 0; mi < 4; ++mi) {
                int r = wrow * 64 + mi * 16 + l16;
                af[mi] = *(const bf16x8*)&As[r * 64 + (((s * 4 + q) ^ (r & 7)) * 8)];
            }
#pragma unroll
            for (int ni = 0; ni < 4; ++ni) {
                int rc = wcol * 64 + ni * 16 + l16;
                bfr[ni] = *(const bf16x8*)&Bs[rc * 64 + (((s * 4 + q) ^ (rc & 7)) * 8)];
            }
#pragma unroll
            for (int mi = 0; mi < 4; ++mi)
#pragma unroll
                for (int ni = 0; ni < 4; ++ni)
                    acc[mi][ni] = __builtin_amdgcn_mfma_f32_16x16x32_bf16(
                        af[mi], bfr[ni], acc[mi][ni], 0, 0, 0);
        }
        __syncthreads();
    }

    // C/D layout (m89-verified): col = lane&15, row = (lane>>4)*4 + reg
    if (fuseW) {
#pragma unroll
        for (int mi = 0; mi < 4; ++mi)
#pragma unroll
            for (int i = 0; i < 4; ++i) {
                float rs = 0.f;
#pragma unroll
                for (int ni = 0; ni < 4; ++ni) {
                    int cc = col0 + wcol * 64 + ni * 16 + l16;
                    float val = acc[mi][ni][i] * scale[cc] + offset[cc];
                    val = val > 0.f ? val : 0.1f * val;
                    rs += val * fuseW[cc];
                }
                rs += __shfl_xor(rs, 1, 64);
                rs += __shfl_xor(rs, 2, 64);
                rs += __shfl_xor(rs, 4, 64);
                rs += __shfl_xor(rs, 8, 64);
                if (l16 == 0) {
                    int r = row0 + wrow * 64 + mi * 16 + q * 4 + i;
                    atomicAdd(facc + (size_t)z * faccStride + r, rs);
                }
            }
        return;
    }
    bf16* Cp = C + (size_t)z * (size_t)batchC;
#pragma unroll
    for (int mi = 0; mi < 4; ++mi)
#pragma unroll
        for (int ni = 0; ni < 4; ++ni)
#pragma unroll
            for (int i = 0; i < 4; ++i) {
                int r = row0 + wrow * 64 + mi * 16 + q * 4 + i;
                int cc = col0 + wcol * 64 + ni * 16 + l16;
                float val = acc[mi][ni][i];
                if (scale) val = val * scale[cc] + offset[cc];
                if (lrelu) val = val > 0.f ? val : 0.1f * val;
                Cp[(size_t)r * N + cc] = (bf16)val;
            }
}

// ---------- gemm_aff (R12-verified): symmetric affinity, 256x128, BK=64 ----
__global__ __launch_bounds__(512) void gemm_aff(
    const float* __restrict__ pairX,
    const float* __restrict__ ps, const float* __restrict__ po,
    const bf16* __restrict__ BT,
    int K,
    const float* __restrict__ scale, const float* __restrict__ offset,
    const float* __restrict__ sclW, float* __restrict__ w_acc)
{
    __shared__ bf16 As[256 * 64];   // 32 KiB
    __shared__ bf16 Bs[128 * 64];   // 16 KiB
    const int tid  = threadIdx.x;
    const int lane = tid & 63;
    const int wave = tid >> 6;
    const int wrow = wave >> 1, wcol = wave & 1;
    const int q = lane >> 4, l16 = lane & 15;
    const int col0 = blockIdx.x * 128;

    int ta = 0, rem = blockIdx.y;
    while (rem >= 16 - ta) { rem -= 16 - ta; ++ta; }
    const int tb = ta + rem;

    f32x4 acc[4][4];
#pragma unroll
    for (int mi = 0; mi < 4; ++mi)
#pragma unroll
        for (int ni = 0; ni < 4; ++ni)
#pragma unroll
            for (int e = 0; e < 4; ++e) acc[mi][ni][e] = 0.f;

    for (int kk = 0; kk < K; kk += 64) {
#pragma unroll
        for (int t = 0; t < 4; ++t) {
            int c = tid + t * 512;          // 2048 tasks: r=c>>3, ch=c&7
            int r = c >> 3, ch = c & 7;
            int g1 = ta * 16 + (r >> 4), g2 = tb * 16 + (r & 15);
            const float* xp = pairX + (size_t)g1 * K + kk + ch * 8;
            const float* yp = pairX + (size_t)g2 * K + kk + ch * 8;
            f32x4 x0 = *(const f32x4*)xp, x1 = *(const f32x4*)(xp + 4);
            f32x4 y0 = *(const f32x4*)yp, y1 = *(const f32x4*)(yp + 4);
            f32x4 sa = *(const f32x4*)(ps + kk + ch * 8);
            f32x4 sb = *(const f32x4*)(ps + kk + ch * 8 + 4);
            f32x4 oa = *(const f32x4*)(po + kk + ch * 8);
            f32x4 ob = *(const f32x4*)(po + kk + ch * 8 + 4);
            bf16x8 dv;
#pragma unroll
            for (int j = 0; j < 4; ++j) {
                float d0 = x0[j] - y0[j];
                float d1 = x1[j] - y1[j];
                dv[j]     = (bf16)(d0 * d0 * sa[j] + oa[j]);
                dv[j + 4] = (bf16)(d1 * d1 * sb[j] + ob[j]);
            }
            *(bf16x8*)&As[r * 64 + ((ch ^ (r & 7)) * 8)] = dv;
        }
#pragma unroll
        for (int t = 0; t < 2; ++t) {
            int idx = t * 512 + tid;        // 1024 chunks
            int r = idx >> 3, sch = idx & 7;
            int gch = sch ^ (r & 7);
            async_load16(BT + (size_t)(col0 + r) * K + kk + gch * 8,
                         &Bs[idx * 8]);
        }
        __syncthreads();

#pragma unroll
        for (int s = 0; s < 2; ++s) {
            bf16x8 af[4], bfr[4];
#pragma unroll
            for (int mi = 0; mi < 4; ++mi) {
                int r = wrow * 64 + mi * 16 + l16;
                af[mi] = *(const bf16x8*)&As[r * 64 + (((s * 4 + q) ^ (r & 7)) * 8)];
            }
#pragma unroll
            for (int ni = 0; ni < 4; ++ni) {
                int rc = wcol * 64 + ni * 16 + l16;
                bfr[ni] = *(const bf16x8*)&Bs[rc * 64 + (((s * 4 + q) ^ (rc & 7)) * 8)];
            }
#pragma unroll
            for (int mi = 0; mi < 4; ++mi)
#pragma unroll
                for (int ni = 0; ni < 4; ++ni)
                    acc[mi][ni] = __builtin_amdgcn_mfma_f32_16x16x32_bf16(
                        af[mi], bfr[ni], acc[mi][ni], 0, 0, 0);
        }
        __syncthreads();
    }

#pragma unroll
    for (int mi = 0; mi < 4; ++mi)
#pragma unroll
        for (int i = 0; i < 4; ++i) {
            float rs = 0.f;
#pragma unroll
            for (int ni = 0; ni < 4; ++ni) {
                int cc = col0 + wcol * 64 + ni * 16 + l16;
                float val = acc[mi][ni][i] * scale[cc] + offset[cc];
                val = val > 0.f ? val : 0.1f * val;
                rs += val * sclW[cc];
            }
            rs += __shfl_xor(rs, 1, 64);
            rs += __shfl_xor(rs, 2, 64);
            rs += __shfl_xor(rs, 4, 64);
            rs += __shfl_xor(rs, 8, 64);
            if (l16 == 0) {
                int r = wrow * 64 + mi * 16 + q * 4 + i;
                int g1 = ta * 16 + (r >> 4), g2 = tb * 16 + (r & 15);
                atomicAdd(w_acc + g1 * 256 + g2, rs);
            }
        }
}

extern "C" void kernel_launch(void* const* d_in, const int* in_sizes, int n_in,
                              void* d_out, int out_size, void* d_ws, size_t ws_size,
                              hipStream_t stream)
{
    const float* f_p   = (const float*)d_in[0];
    const float* f_g   = (const float*)d_in[1];
    const float* bn_g  = (const float*)d_in[2];
    const float* bn_b  = (const float*)d_in[3];
    const float* bn_m  = (const float*)d_in[4];
    const float* bn_v  = (const float*)d_in[5];
    const float* rf_W1 = (const float*)d_in[6];
    const float* rf_b1 = (const float*)d_in[7];
    const float* rf1_g = (const float*)d_in[8];
    const float* rf1_b = (const float*)d_in[9];
    const float* rf1_m = (const float*)d_in[10];
    const float* rf1_v = (const float*)d_in[11];
    const float* rf_W2 = (const float*)d_in[12];
    const float* rf_b2 = (const float*)d_in[13];
    const float* rf2_g = (const float*)d_in[14];
    const float* rf2_b = (const float*)d_in[15];
    const float* rf2_m = (const float*)d_in[16];
    const float* rf2_v = (const float*)d_in[17];
    const float* sfc_W = (const float*)d_in[18];
    const float* sfc_b = (const float*)d_in[19];
    const float* sbn_g = (const float*)d_in[20];
    const float* sbn_b = (const float*)d_in[21];
    const float* sbn_m = (const float*)d_in[22];
    const float* sbn_v = (const float*)d_in[23];
    const float* scl_W = (const float*)d_in[24];
    const float* scl_b = (const float*)d_in[25];
    const float* ffc_W = (const float*)d_in[26];
    const float* ffc_b = (const float*)d_in[27];
    const float* fbn_g = (const float*)d_in[28];
    const float* fbn_b = (const float*)d_in[29];
    const float* fbn_m = (const float*)d_in[30];
    const float* fbn_v = (const float*)d_in[31];
    const float* cls_W = (const float*)d_in[32];
    const float* cls_b = (const float*)d_in[33];

    const size_t MB = 1ull << 20;
    char* ws = (char*)d_ws;
    float* SC      = (float*)(ws);
    float *s0 = SC,        *o0 = SC + 1024;
    float *s1 = SC + 2048, *o1 = SC + 3072;
    float *s2 = SC + 4096, *o2 = SC + 5120;
    float *s3 = SC + 6144, *o3 = SC + 6656;
    float *s4 = SC + 7168, *o4 = SC + 7680;
    float* w_acc   = (float*)(ws + 65536);       // 256 KiB
    float* out_acc = (float*)(ws + 327680);      // 128 KiB
    bf16* wT       = (bf16*)(ws + 458752);       // 128 KiB
    bf16* W1T      = (bf16*)(ws + 1 * MB);
    bf16* W2T      = (bf16*)(ws + 3 * MB);
    bf16* sfcT     = (bf16*)(ws + 5 * MB);
    bf16* ffcT     = (bf16*)(ws + 6 * MB);

    int nc;
    if      (ws_size >= 170 * MB) nc = 1;        // confirmed since R3
    else if (ws_size >= 90 * MB)  nc = 2;
    else                          nc = 4;
    const int pc = 128 / nc;
    const int R  = pc * 256;
    const size_t hbytes = (size_t)R * 1024 * 2;
    bf16* bufA = (bf16*)(ws + 8 * MB);                    // h
    bf16* bufB = (bf16*)(ws + 8 * MB + hbytes);           // t
    bf16* bufC = (bf16*)(ws + 8 * MB + 2 * hbytes);       // uT [pc][512][256]

    // 1. BN folds
    prep_kernel<<<dim3(4), 256, 0, stream>>>(bn_g, bn_b, bn_m, bn_v, nullptr, s0, o0, 1024);
    prep_kernel<<<dim3(4), 256, 0, stream>>>(rf1_g, rf1_b, rf1_m, rf1_v, rf_b1, s1, o1, 1024);
    prep_kernel<<<dim3(4), 256, 0, stream>>>(rf2_g, rf2_b, rf2_m, rf2_v, rf_b2, s2, o2, 1024);
    prep_kernel<<<dim3(2), 256, 0, stream>>>(sbn_g, sbn_b, sbn_m, sbn_v, sfc_b, s3, o3, 512);
    prep_kernel<<<dim3(2), 256, 0, stream>>>(fbn_g, fbn_b, fbn_m, fbn_v, ffc_b, s4, o4, 512);

    // 2. weight transposes (f32 -> bf16)
    wtrans_kernel<<<dim3(4, 1024), 256, 0, stream>>>(rf_W1, W1T, 1024, 1024);
    wtrans_kernel<<<dim3(4, 1024), 256, 0, stream>>>(rf_W2, W2T, 1024, 1024);
    wtrans_kernel<<<dim3(4, 512), 256, 0, stream>>>(sfc_W, sfcT, 1024, 512);
    wtrans_kernel<<<dim3(4, 512), 256, 0, stream>>>(ffc_W, ffcT, 1024, 512);

    // 3. zero accumulators (w_acc + out_acc contiguous)
    hipMemsetAsync(ws + 65536, 0, 393216, stream);

    // 4. symmetric affinity (R12-verified): grid (4,136)
    gemm_aff<<<dim3(4, 136), 512, 0, stream>>>(
        f_g, s0, o0, sfcT, 1024, s3, o3, scl_W, w_acc);
    // 5. wT[g2][g1] = bf16(w[canon] + scl_b)
    wconv_kernel<<<dim3(256), 256, 0, stream>>>(w_acc, scl_b, wT);

    // 6. probe chunks (all worker gemms now 128^2-tile gemm128)
    for (int ci = 0; ci < nc; ++ci) {
        // h = lrelu(rf1(d @ W1 + b1))   [R,1024] (pair-fused)
        gemm128<true><<<dim3(8, R / 128), 256, 0, stream>>>(
            nullptr, f_p, f_g, s0, o0, W1T, bufA, 1024, 1024, ci * R,
            0, 0, 0, s1, o1, 1, nullptr, nullptr, 0);
        // t = lrelu(rf2(h @ W2 + b2))   [R,1024]
        gemm128<false><<<dim3(8, R / 128), 256, 0, stream>>>(
            bufA, nullptr, nullptr, nullptr, nullptr, W2T, bufB, 1024, 1024, 0,
            0, 0, 0, s2, o2, 1, nullptr, nullptr, 0);
        // uT_p = ffcT @ t_p^T           [pc][512][256]  (batched; no utrans)
        gemm128<false><<<dim3(2, 4, pc), 256, 0, stream>>>(
            ffcT, nullptr, nullptr, nullptr, nullptr, bufB, bufC, 1024, 256, 0,
            0, (long long)256 * 1024, (long long)512 * 256,
            nullptr, nullptr, 0, nullptr, nullptr, 0);
        // feat_p = lrelu(fbn(wT @ uT_p^T + b)) . cls_W -> out_acc  (batched)
        gemm128<false><<<dim3(4, 2, pc), 256, 0, stream>>>(
            wT, nullptr, nullptr, nullptr, nullptr, bufC, nullptr, 256, 512, 0,
            0, (long long)512 * 256, 0,
            s4, o4, 1, cls_W, out_acc + (size_t)ci * pc * 256, 256);
    }
    // 7. d_out = out_acc + cls_b
    finout_kernel<<<dim3(128), 256, 0, stream>>>(out_acc, cls_b, (float*)d_out);
}

// Round 4
// 547.682 us; speedup vs baseline: 1.1549x; 1.1549x over previous
//
#include <hip/hip_runtime.h>

// Sggnn_23218593202512 — round 17: un-fuse d. R16 falsified the occupancy
// theory (VGPR_Count excludes AGPRs; still 2 waves/SIMD) and exposed the
// real h-gemm cost: PAIR staging re-reads ~256KB f32 per K-step per block
// from L2 (~2.1GB L2 traffic, VALUBusy 35% at 128^2 tiles with 8x col
// redundancy). Fix: dprep_kernel computes d ONCE as bf16 [R,1024] (aliased
// onto bufB, dead until t-gemm overwrites it), and ALL worker gemms become
// uniform pure-async 256^2 counted-vmcnt (R15 structure, the best so far:
// 155us h / 561 total). A-staging bytes per K-step drop 8x (32KB bf16 vs
// 256KB f32), pair VALU work drops 4x (computed once not per-col-block),
// and vmcnt(8) counting is now exact (only global_load_lds in flight).
// Plus bijective XCD swizzle on h/t (nwg=512, %8==0): the 4 col-blocks of
// an A row-panel stay on one XCD -> A-panel read ~once into its L2.
// gemm_aff / prep / wtrans / wconv / finout byte-identical to R15/R16.

typedef __bf16 bf16;
typedef __attribute__((ext_vector_type(8))) __bf16 bf16x8;
typedef __attribute__((ext_vector_type(4))) float f32x4;

#define EPSV 1e-5f

__device__ __forceinline__ void async_load16(const bf16* g, bf16* l) {
    __builtin_amdgcn_global_load_lds(
        (const __attribute__((address_space(1))) void*)g,
        (__attribute__((address_space(3))) void*)l, 16, 0, 0);
}

__global__ __launch_bounds__(256) void prep_kernel(
    const float* __restrict__ g, const float* __restrict__ b,
    const float* __restrict__ m, const float* __restrict__ v,
    const float* __restrict__ bias, float* __restrict__ scale,
    float* __restrict__ offset, int n)
{
    int i = blockIdx.x * 256 + threadIdx.x;
    if (i >= n) return;
    float s = g[i] / sqrtf(v[i] + EPSV);
    float o = b[i] - m[i] * s;
    if (bias) o += bias[i] * s;
    scale[i] = s;
    offset[i] = o;
}

__global__ __launch_bounds__(256) void wtrans_kernel(
    const float* __restrict__ in, bf16* __restrict__ out, int K, int N)
{
    int k = blockIdx.x * 256 + threadIdx.x;
    int n = blockIdx.y;
    out[(size_t)n * K + k] = (bf16)in[(size_t)k * N + n];
}

// wT[g2*256+g1] = bf16(w[g1][g2] + scl_b); only g-tiles ta<=tb computed,
// mirror otherwise (w symmetric). [R11/R12-verified]
__global__ __launch_bounds__(256) void wconv_kernel(
    const float* __restrict__ w_acc, const float* __restrict__ sclb,
    bf16* __restrict__ wT)
{
    int tid = blockIdx.x * 256 + threadIdx.x;
    int g2 = tid >> 8, g1 = tid & 255;
    int idx = ((g1 >> 4) <= (g2 >> 4)) ? (g1 * 256 + g2) : (g2 * 256 + g1);
    wT[tid] = (bf16)(w_acc[idx] + sclb[0]);
}

__global__ __launch_bounds__(256) void finout_kernel(
    const float* __restrict__ acc, const float* __restrict__ clsb,
    float* __restrict__ out)
{
    int i = blockIdx.x * 256 + threadIdx.x;
    out[i] = acc[i] + clsb[0];
}

// d[r][k] = bf16((f_p[gr>>8][k] - f_g[gr&255][k])^2 * ps[k] + po[k]),
// gr = rowOff + r. One bf16x8 per thread; writes coalesced 16B.
// f_p/f_g are 1.5MB total -> L2-resident; pass is HBM-write-bound (~12us).
__global__ __launch_bounds__(256) void dprep_kernel(
    const float* __restrict__ X, const float* __restrict__ Y,
    const float* __restrict__ ps, const float* __restrict__ po,
    bf16* __restrict__ d, int rowOff)
{
    int t  = blockIdx.x * 256 + threadIdx.x;
    int k0 = (t & 127) * 8;           // 128 threads span one 1024-wide row
    int r  = t >> 7;
    int gr = rowOff + r;
    const float* xp = X + (size_t)(gr >> 8) * 1024 + k0;
    const float* yp = Y + (size_t)(gr & 255) * 1024 + k0;
    f32x4 x0 = *(const f32x4*)xp, x1 = *(const f32x4*)(xp + 4);
    f32x4 y0 = *(const f32x4*)yp, y1 = *(const f32x4*)(yp + 4);
    f32x4 sa = *(const f32x4*)(ps + k0), sb = *(const f32x4*)(ps + k0 + 4);
    f32x4 oa = *(const f32x4*)(po + k0), ob = *(const f32x4*)(po + k0 + 4);
    bf16x8 dv;
#pragma unroll
    for (int j = 0; j < 4; ++j) {
        float d0 = x0[j] - y0[j];
        float d1 = x1[j] - y1[j];
        dv[j]     = (bf16)(d0 * d0 * sa[j] + oa[j]);
        dv[j + 4] = (bf16)(d1 * d1 * sb[j] + ob[j]);
    }
    *(bf16x8*)&d[(size_t)r * 1024 + k0] = dv;
}

// ---------- gemm256 (R17: pure-async counted-vmcnt pipeline) --------------
// C_z[M,N] = epi(A_z[M,K] @ BT_z[N,K]^T). 256x256 block, 512 thr = 8 waves
// (2 row x 4 col), wave 128x64 (acc[8][4]), BK=64, XOR-swizzled LDS,
// LDS = 2 x (As 32K + Bs 32K) = 128 KiB double buffer.
// Main loop per K-tile t: stage(t+1 -> buf^1) [8 async loads] ->
// s_waitcnt vmcnt(8) [tile-t complete, tile-t+1 in flight] -> s_barrier ->
// ds_read + 64 MFMA -> s_barrier (WAR guard).
// XCD swizzle (bijective, requires nwg%8==0) applied when gridDim.z==1:
// each XCD gets a contiguous chunk of row-panels -> A-panel L2 reuse.
// fuse (fuseW!=0): rs += lrelu(bn(val))*fuseW[col] ->
//   atomicAdd facc[z*faccStride + global row].
__global__ __launch_bounds__(512) void gemm256(
    const bf16* __restrict__ A,
    const bf16* __restrict__ BT,
    bf16* __restrict__ C,
    int K, int N,
    long long batchA, long long batchB, long long batchC,
    const float* __restrict__ scale, const float* __restrict__ offset,
    int lrelu,
    const float* __restrict__ fuseW, float* __restrict__ facc,
    long long faccStride)
{
    __shared__ bf16 As[2 * 256 * 64];   // 64 KiB (double buffer)
    __shared__ bf16 Bs[2 * 256 * 64];   // 64 KiB (double buffer)
    const int tid  = threadIdx.x;
    const int lane = tid & 63;
    const int wave = tid >> 6;
    const int wrow = wave >> 2, wcol = wave & 3;
    const int q = lane >> 4, l16 = lane & 15;
    const int z = blockIdx.z;

    // XCD-aware bijective swizzle (x fastest in dispatch order).
    int bx = blockIdx.x, by = blockIdx.y;
    {
        int nwg = gridDim.x * gridDim.y;
        if (gridDim.z == 1 && (nwg & 7) == 0) {
            int lin = by * gridDim.x + bx;
            int cpx = nwg >> 3;
            int s = (lin & 7) * cpx + (lin >> 3);
            bx = s % gridDim.x;
            by = s / gridDim.x;
        }
    }
    const int row0 = by * 256;
    const int col0 = bx * 256;

    const bf16* Ap = A + (size_t)z * (size_t)batchA;
    const bf16* Bp = BT + (size_t)z * (size_t)batchB;

    f32x4 acc[8][4];
#pragma unroll
    for (int mi = 0; mi < 8; ++mi)
#pragma unroll
        for (int ni = 0; ni < 4; ++ni)
#pragma unroll
            for (int e = 0; e < 4; ++e) acc[mi][ni][e] = 0.f;

    auto stageA = [&](int kk, bf16* dst) {
#pragma unroll
        for (int t = 0; t < 4; ++t) {
            int idx = t * 512 + tid;
            int r = idx >> 3, sch = idx & 7;
            int gch = sch ^ (r & 7);
            async_load16(Ap + (size_t)(row0 + r) * K + kk + gch * 8,
                         &dst[idx * 8]);
        }
    };
    auto stageB = [&](int kk, bf16* dst) {
#pragma unroll
        for (int t = 0; t < 4; ++t) {
            int idx = t * 512 + tid;
            int r = idx >> 3, sch = idx & 7;
            int gch = sch ^ (r & 7);
            async_load16(Bp + (size_t)(col0 + r) * K + kk + gch * 8,
                         &dst[idx * 8]);
        }
    };

    // prologue: fill buffer 0
    stageA(0, As);
    stageB(0, Bs);

    int cur = 0;
    const int nt = K >> 6;
    for (int t = 0; t < nt; ++t) {
        const bool pf = (t + 1) < nt;
        if (pf) {
            stageA(t * 64 + 64, As + (cur ^ 1) * 16384);
            stageB(t * 64 + 64, Bs + (cur ^ 1) * 16384);
        }
        // Tile-t data complete (issued a full compute phase ago); tile-t+1's
        // 8 just-issued loads stay in flight across the barrier.
        if (pf) {
            asm volatile("s_waitcnt vmcnt(8)\n\ts_barrier" ::: "memory");
        } else {
            asm volatile("s_waitcnt vmcnt(0) lgkmcnt(0)\n\ts_barrier"
                         ::: "memory");
        }

        const bf16* Asb = As + cur * 16384;
        const bf16* Bsb = Bs + cur * 16384;
#pragma unroll
        for (int s = 0; s < 2; ++s) {
            bf16x8 af[8], bfr[4];
#pragma unroll
            for (int mi = 0; mi < 8; ++mi) {
                int r = wrow * 128 + mi * 16 + l16;
                af[mi] = *(const bf16x8*)&Asb[r * 64 + (((s * 4 + q) ^ (r & 7)) * 8)];
            }
#pragma unroll
            for (int ni = 0; ni < 4; ++ni) {
                int rc = wcol * 64 + ni * 16 + l16;
                bfr[ni] = *(const bf16x8*)&Bsb[rc * 64 + (((s * 4 + q) ^ (rc & 7)) * 8)];
            }
#pragma unroll
            for (int mi = 0; mi < 8; ++mi)
#pragma unroll
                for (int ni = 0; ni < 4; ++ni)
                    acc[mi][ni] = __builtin_amdgcn_mfma_f32_16x16x32_bf16(
                        af[mi], bfr[ni], acc[mi][ni], 0, 0, 0);
        }
        // WAR guard: all waves done reading buf[cur] before next restage.
        if (pf) asm volatile("s_barrier" ::: "memory");
        cur ^= 1;
    }

    // C/D layout (m89-verified): col = lane&15, row = (lane>>4)*4 + reg
    if (fuseW) {
#pragma unroll
        for (int mi = 0; mi < 8; ++mi)
#pragma unroll
            for (int i = 0; i < 4; ++i) {
                float rs = 0.f;
#pragma unroll
                for (int ni = 0; ni < 4; ++ni) {
                    int cc = col0 + wcol * 64 + ni * 16 + l16;
                    float val = acc[mi][ni][i] * scale[cc] + offset[cc];
                    val = val > 0.f ? val : 0.1f * val;
                    rs += val * fuseW[cc];
                }
                rs += __shfl_xor(rs, 1, 64);
                rs += __shfl_xor(rs, 2, 64);
                rs += __shfl_xor(rs, 4, 64);
                rs += __shfl_xor(rs, 8, 64);
                if (l16 == 0) {
                    int r = row0 + wrow * 128 + mi * 16 + q * 4 + i;
                    atomicAdd(facc + (size_t)z * faccStride + r, rs);
                }
            }
        return;
    }
    bf16* Cp = C + (size_t)z * (size_t)batchC;
#pragma unroll
    for (int mi = 0; mi < 8; ++mi)
#pragma unroll
        for (int ni = 0; ni < 4; ++ni)
#pragma unroll
            for (int i = 0; i < 4; ++i) {
                int r = row0 + wrow * 128 + mi * 16 + q * 4 + i;
                int cc = col0 + wcol * 64 + ni * 16 + l16;
                float val = acc[mi][ni][i];
                if (scale) val = val * scale[cc] + offset[cc];
                if (lrelu) val = val > 0.f ? val : 0.1f * val;
                Cp[(size_t)r * N + cc] = (bf16)val;
            }
}

// ---------- gemm_aff (R12-verified): symmetric affinity, 256x128, BK=64 ----
__global__ __launch_bounds__(512) void gemm_aff(
    const float* __restrict__ pairX,
    const float* __restrict__ ps, const float* __restrict__ po,
    const bf16* __restrict__ BT,
    int K,
    const float* __restrict__ scale, const float* __restrict__ offset,
    const float* __restrict__ sclW, float* __restrict__ w_acc)
{
    __shared__ bf16 As[256 * 64];   // 32 KiB
    __shared__ bf16 Bs[128 * 64];   // 16 KiB
    const int tid  = threadIdx.x;
    const int lane = tid & 63;
    const int wave = tid >> 6;
    const int wrow = wave >> 1, wcol = wave & 1;
    const int q = lane >> 4, l16 = lane & 15;
    const int col0 = blockIdx.x * 128;

    int ta = 0, rem = blockIdx.y;
    while (rem >= 16 - ta) { rem -= 16 - ta; ++ta; }
    const int tb = ta + rem;

    f32x4 acc[4][4];
#pragma unroll
    for (int mi = 0; mi < 4; ++mi)
#pragma unroll
        for (int ni = 0; ni < 4; ++ni)
#pragma unroll
            for (int e = 0; e < 4; ++e) acc[mi][ni][e] = 0.f;

    for (int kk = 0; kk < K; kk += 64) {
#pragma unroll
        for (int t = 0; t < 4; ++t) {
            int c = tid + t * 512;          // 2048 tasks: r=c>>3, ch=c&7
            int r = c >> 3, ch = c & 7;
            int g1 = ta * 16 + (r >> 4), g2 = tb * 16 + (r & 15);
            const float* xp = pairX + (size_t)g1 * K + kk + ch * 8;
            const float* yp = pairX + (size_t)g2 * K + kk + ch * 8;
            f32x4 x0 = *(const f32x4*)xp, x1 = *(const f32x4*)(xp + 4);
            f32x4 y0 = *(const f32x4*)yp, y1 = *(const f32x4*)(yp + 4);
            f32x4 sa = *(const f32x4*)(ps + kk + ch * 8);
            f32x4 sb = *(const f32x4*)(ps + kk + ch * 8 + 4);
            f32x4 oa = *(const f32x4*)(po + kk + ch * 8);
            f32x4 ob = *(const f32x4*)(po + kk + ch * 8 + 4);
            bf16x8 dv;
#pragma unroll
            for (int j = 0; j < 4; ++j) {
                float d0 = x0[j] - y0[j];
                float d1 = x1[j] - y1[j];
                dv[j]     = (bf16)(d0 * d0 * sa[j] + oa[j]);
                dv[j + 4] = (bf16)(d1 * d1 * sb[j] + ob[j]);
            }
            *(bf16x8*)&As[r * 64 + ((ch ^ (r & 7)) * 8)] = dv;
        }
#pragma unroll
        for (int t = 0; t < 2; ++t) {
            int idx = t * 512 + tid;        // 1024 chunks
            int r = idx >> 3, sch = idx & 7;
            int gch = sch ^ (r & 7);
            async_load16(BT + (size_t)(col0 + r) * K + kk + gch * 8,
                         &Bs[idx * 8]);
        }
        __syncthreads();

#pragma unroll
        for (int s = 0; s < 2; ++s) {
            bf16x8 af[4], bfr[4];
#pragma unroll
            for (int mi = 0; mi < 4; ++mi) {
                int r = wrow * 64 + mi * 16 + l16;
                af[mi] = *(const bf16x8*)&As[r * 64 + (((s * 4 + q) ^ (r & 7)) * 8)];
            }
#pragma unroll
            for (int ni = 0; ni < 4; ++ni) {
                int rc = wcol * 64 + ni * 16 + l16;
                bfr[ni] = *(const bf16x8*)&Bs[rc * 64 + (((s * 4 + q) ^ (rc & 7)) * 8)];
            }
#pragma unroll
            for (int mi = 0; mi < 4; ++mi)
#pragma unroll
                for (int ni = 0; ni < 4; ++ni)
                    acc[mi][ni] = __builtin_amdgcn_mfma_f32_16x16x32_bf16(
                        af[mi], bfr[ni], acc[mi][ni], 0, 0, 0);
        }
        __syncthreads();
    }

#pragma unroll
    for (int mi = 0; mi < 4; ++mi)
#pragma unroll
        for (int i = 0; i < 4; ++i) {
            float rs = 0.f;
#pragma unroll
            for (int ni = 0; ni < 4; ++ni) {
                int cc = col0 + wcol * 64 + ni * 16 + l16;
                float val = acc[mi][ni][i] * scale[cc] + offset[cc];
                val = val > 0.f ? val : 0.1f * val;
                rs += val * sclW[cc];
            }
            rs += __shfl_xor(rs, 1, 64);
            rs += __shfl_xor(rs, 2, 64);
            rs += __shfl_xor(rs, 4, 64);
            rs += __shfl_xor(rs, 8, 64);
            if (l16 == 0) {
                int r = wrow * 64 + mi * 16 + q * 4 + i;
                int g1 = ta * 16 + (r >> 4), g2 = tb * 16 + (r & 15);
                atomicAdd(w_acc + g1 * 256 + g2, rs);
            }
        }
}

extern "C" void kernel_launch(void* const* d_in, const int* in_sizes, int n_in,
                              void* d_out, int out_size, void* d_ws, size_t ws_size,
                              hipStream_t stream)
{
    const float* f_p   = (const float*)d_in[0];
    const float* f_g   = (const float*)d_in[1];
    const float* bn_g  = (const float*)d_in[2];
    const float* bn_b  = (const float*)d_in[3];
    const float* bn_m  = (const float*)d_in[4];
    const float* bn_v  = (const float*)d_in[5];
    const float* rf_W1 = (const float*)d_in[6];
    const float* rf_b1 = (const float*)d_in[7];
    const float* rf1_g = (const float*)d_in[8];
    const float* rf1_b = (const float*)d_in[9];
    const float* rf1_m = (const float*)d_in[10];
    const float* rf1_v = (const float*)d_in[11];
    const float* rf_W2 = (const float*)d_in[12];
    const float* rf_b2 = (const float*)d_in[13];
    const float* rf2_g = (const float*)d_in[14];
    const float* rf2_b = (const float*)d_in[15];
    const float* rf2_m = (const float*)d_in[16];
    const float* rf2_v = (const float*)d_in[17];
    const float* sfc_W = (const float*)d_in[18];
    const float* sfc_b = (const float*)d_in[19];
    const float* sbn_g = (const float*)d_in[20];
    const float* sbn_b = (const float*)d_in[21];
    const float* sbn_m = (const float*)d_in[22];
    const float* sbn_v = (const float*)d_in[23];
    const float* scl_W = (const float*)d_in[24];
    const float* scl_b = (const float*)d_in[25];
    const float* ffc_W = (const float*)d_in[26];
    const float* ffc_b = (const float*)d_in[27];
    const float* fbn_g = (const float*)d_in[28];
    const float* fbn_b = (const float*)d_in[29];
    const float* fbn_m = (const float*)d_in[30];
    const float* fbn_v = (const float*)d_in[31];
    const float* cls_W = (const float*)d_in[32];
    const float* cls_b = (const float*)d_in[33];

    const size_t MB = 1ull << 20;
    char* ws = (char*)d_ws;
    float* SC      = (float*)(ws);
    float *s0 = SC,        *o0 = SC + 1024;
    float *s1 = SC + 2048, *o1 = SC + 3072;
    float *s2 = SC + 4096, *o2 = SC + 5120;
    float *s3 = SC + 6144, *o3 = SC + 6656;
    float *s4 = SC + 7168, *o4 = SC + 7680;
    float* w_acc   = (float*)(ws + 65536);       // 256 KiB
    float* out_acc = (float*)(ws + 327680);      // 128 KiB
    bf16* wT       = (bf16*)(ws + 458752);       // 128 KiB
    bf16* W1T      = (bf16*)(ws + 1 * MB);
    bf16* W2T      = (bf16*)(ws + 3 * MB);
    bf16* sfcT     = (bf16*)(ws + 5 * MB);
    bf16* ffcT     = (bf16*)(ws + 6 * MB);

    int nc;
    if      (ws_size >= 170 * MB) nc = 1;        // confirmed since R3
    else if (ws_size >= 90 * MB)  nc = 2;
    else                          nc = 4;
    const int pc = 128 / nc;
    const int R  = pc * 256;
    const size_t hbytes = (size_t)R * 1024 * 2;
    bf16* bufA = (bf16*)(ws + 8 * MB);                    // h
    bf16* bufB = (bf16*)(ws + 8 * MB + hbytes);           // d, then t
    bf16* bufC = (bf16*)(ws + 8 * MB + 2 * hbytes);       // uT [pc][512][256]

    // 1. BN folds
    prep_kernel<<<dim3(4), 256, 0, stream>>>(bn_g, bn_b, bn_m, bn_v, nullptr, s0, o0, 1024);
    prep_kernel<<<dim3(4), 256, 0, stream>>>(rf1_g, rf1_b, rf1_m, rf1_v, rf_b1, s1, o1, 1024);
    prep_kernel<<<dim3(4), 256, 0, stream>>>(rf2_g, rf2_b, rf2_m, rf2_v, rf_b2, s2, o2, 1024);
    prep_kernel<<<dim3(2), 256, 0, stream>>>(sbn_g, sbn_b, sbn_m, sbn_v, sfc_b, s3, o3, 512);
    prep_kernel<<<dim3(2), 256, 0, stream>>>(fbn_g, fbn_b, fbn_m, fbn_v, ffc_b, s4, o4, 512);

    // 2. weight transposes (f32 -> bf16)
    wtrans_kernel<<<dim3(4, 1024), 256, 0, stream>>>(rf_W1, W1T, 1024, 1024);
    wtrans_kernel<<<dim3(4, 1024), 256, 0, stream>>>(rf_W2, W2T, 1024, 1024);
    wtrans_kernel<<<dim3(4, 512), 256, 0, stream>>>(sfc_W, sfcT, 1024, 512);
    wtrans_kernel<<<dim3(4, 512), 256, 0, stream>>>(ffc_W, ffcT, 1024, 512);

    // 3. zero accumulators (w_acc + out_acc contiguous)
    hipMemsetAsync(ws + 65536, 0, 393216, stream);

    // 4. symmetric affinity (R12-verified): grid (4,136)
    gemm_aff<<<dim3(4, 136), 512, 0, stream>>>(
        f_g, s0, o0, sfcT, 1024, s3, o3, scl_W, w_acc);
    // 5. wT[g2][g1] = bf16(w[canon] + scl_b)
    wconv_kernel<<<dim3(256), 256, 0, stream>>>(w_acc, scl_b, wT);

    // 6. probe chunks (all gemms pure-async; d precomputed into bufB)
    for (int ci = 0; ci < nc; ++ci) {
        // d = bn1((f_p - f_g)^2)        [R,1024] bf16 -> bufB (dead after h)
        dprep_kernel<<<dim3(R / 2), 256, 0, stream>>>(
            f_p, f_g, s0, o0, bufB, ci * R);
        // h = lrelu(rf1(d @ W1 + b1))   [R,1024]
        gemm256<<<dim3(4, R / 256), 512, 0, stream>>>(
            bufB, W1T, bufA, 1024, 1024,
            0, 0, 0, s1, o1, 1, nullptr, nullptr, 0);
        // t = lrelu(rf2(h @ W2 + b2))   [R,1024] (overwrites d: dead)
        gemm256<<<dim3(4, R / 256), 512, 0, stream>>>(
            bufA, W2T, bufB, 1024, 1024,
            0, 0, 0, s2, o2, 1, nullptr, nullptr, 0);
        // uT_p = ffcT @ t_p^T           [pc][512][256]  (batched)
        gemm256<<<dim3(1, 2, pc), 512, 0, stream>>>(
            ffcT, bufB, bufC, 1024, 256,
            0, (long long)256 * 1024, (long long)512 * 256,
            nullptr, nullptr, 0, nullptr, nullptr, 0);
        // feat_p = lrelu(fbn(wT @ uT_p^T + b)) . cls_W -> out_acc  (batched)
        gemm256<<<dim3(2, 1, pc), 512, 0, stream>>>(
            wT, bufC, nullptr, 256, 512,
            0, (long long)512 * 256, 0,
            s4, o4, 1, cls_W, out_acc + (size_t)ci * pc * 256, 256);
    }
    // 7. d_out = out_acc + cls_b
    finout_kernel<<<dim3(128), 256, 0, stream>>>(out_acc, cls_b, (float*)d_out);
}

// Round 5
// 520.887 us; speedup vs baseline: 1.2143x; 1.0514x over previous
//
#include <hip/hip_runtime.h>

// Sggnn_23218593202512 — round 18: 8-phase schedule (T3+T4+T5) on the
// worker gemm. R17 landed at 619 TF = the documented 2-phase ceiling
// (m233/m248: 607-682); catalog says the remaining levers (phase-split,
// setprio) require the 8-phase interleave. Port per §5 template with a
// region-consumption proof (buf0=even tiles, buf1=odd tiles):
//   consumption: buf0.B free after ph1, buf0.A after ph4, buf1.B after
//   ph5, buf1.A after ph8 (reads complete at mid-phase lgkmcnt(0), made
//   global by phase-end barrier).
//   staging slots: ph1/2 buf1.A<-tile(T+1), ph3/4 buf0.B<-tile(T+2),
//   ph5/6 buf0.A<-tile(T+2), ph7/8 buf1.B<-tile(T+3). 2 loads per slot.
//   vmcnt(4) at ph4: outstanding = ph1..4 stages (8) [+<=4 prologue
//   remnant] -> all but 4 newest landed -> buf1.A (+prev buf1.B) landed
//   before ph5 reads. vmcnt(4) at ph8: -> buf0.B+buf0.A landed before
//   next ph1 reads. Last iteration: vmcnt(0) at ph4 (drains the tail's
//   buf1.A), no further stages. MFMA order unchanged -> bit-identical.
// dprep / gemm_aff / prep / wtrans / wconv / finout byte-identical to R17.

typedef __bf16 bf16;
typedef __attribute__((ext_vector_type(8))) __bf16 bf16x8;
typedef __attribute__((ext_vector_type(4))) float f32x4;

#define EPSV 1e-5f

__device__ __forceinline__ void async_load16(const bf16* g, bf16* l) {
    __builtin_amdgcn_global_load_lds(
        (const __attribute__((address_space(1))) void*)g,
        (__attribute__((address_space(3))) void*)l, 16, 0, 0);
}

__global__ __launch_bounds__(256) void prep_kernel(
    const float* __restrict__ g, const float* __restrict__ b,
    const float* __restrict__ m, const float* __restrict__ v,
    const float* __restrict__ bias, float* __restrict__ scale,
    float* __restrict__ offset, int n)
{
    int i = blockIdx.x * 256 + threadIdx.x;
    if (i >= n) return;
    float s = g[i] / sqrtf(v[i] + EPSV);
    float o = b[i] - m[i] * s;
    if (bias) o += bias[i] * s;
    scale[i] = s;
    offset[i] = o;
}

__global__ __launch_bounds__(256) void wtrans_kernel(
    const float* __restrict__ in, bf16* __restrict__ out, int K, int N)
{
    int k = blockIdx.x * 256 + threadIdx.x;
    int n = blockIdx.y;
    out[(size_t)n * K + k] = (bf16)in[(size_t)k * N + n];
}

// wT[g2*256+g1] = bf16(w[g1][g2] + scl_b); only g-tiles ta<=tb computed,
// mirror otherwise (w symmetric). [R11/R12-verified]
__global__ __launch_bounds__(256) void wconv_kernel(
    const float* __restrict__ w_acc, const float* __restrict__ sclb,
    bf16* __restrict__ wT)
{
    int tid = blockIdx.x * 256 + threadIdx.x;
    int g2 = tid >> 8, g1 = tid & 255;
    int idx = ((g1 >> 4) <= (g2 >> 4)) ? (g1 * 256 + g2) : (g2 * 256 + g1);
    wT[tid] = (bf16)(w_acc[idx] + sclb[0]);
}

__global__ __launch_bounds__(256) void finout_kernel(
    const float* __restrict__ acc, const float* __restrict__ clsb,
    float* __restrict__ out)
{
    int i = blockIdx.x * 256 + threadIdx.x;
    out[i] = acc[i] + clsb[0];
}

// d[r][k] = bf16((f_p[gr>>8][k] - f_g[gr&255][k])^2 * ps[k] + po[k]),
// gr = rowOff + r. One bf16x8 per thread; writes coalesced 16B.
__global__ __launch_bounds__(256) void dprep_kernel(
    const float* __restrict__ X, const float* __restrict__ Y,
    const float* __restrict__ ps, const float* __restrict__ po,
    bf16* __restrict__ d, int rowOff)
{
    int t  = blockIdx.x * 256 + threadIdx.x;
    int k0 = (t & 127) * 8;           // 128 threads span one 1024-wide row
    int r  = t >> 7;
    int gr = rowOff + r;
    const float* xp = X + (size_t)(gr >> 8) * 1024 + k0;
    const float* yp = Y + (size_t)(gr & 255) * 1024 + k0;
    f32x4 x0 = *(const f32x4*)xp, x1 = *(const f32x4*)(xp + 4);
    f32x4 y0 = *(const f32x4*)yp, y1 = *(const f32x4*)(yp + 4);
    f32x4 sa = *(const f32x4*)(ps + k0), sb = *(const f32x4*)(ps + k0 + 4);
    f32x4 oa = *(const f32x4*)(po + k0), ob = *(const f32x4*)(po + k0 + 4);
    bf16x8 dv;
#pragma unroll
    for (int j = 0; j < 4; ++j) {
        float d0 = x0[j] - y0[j];
        float d1 = x1[j] - y1[j];
        dv[j]     = (bf16)(d0 * d0 * sa[j] + oa[j]);
        dv[j + 4] = (bf16)(d1 * d1 * sb[j] + ob[j]);
    }
    *(bf16x8*)&d[(size_t)r * 1024 + k0] = dv;
}

// One phase: {ds_read A-quad Q (+ all B if READB) ; STAGE ; VM ;
//             barrier ; lgkmcnt(0) ; setprio(1) 16 MFMA setprio(0) ;
//             barrier}. Q is a literal -> all acc indices compile-time.
#define PHASE(ASB, BSB, Q, READB, STAGE_STMT, VM_STMT)                        \
  {                                                                           \
    if (READB) {                                                              \
      _Pragma("unroll") for (int ni = 0; ni < 4; ++ni) {                      \
        int rc = wcol * 64 + ni * 16 + l16;                                   \
        bfr[ni][0] = *(const bf16x8*)&(BSB)[rc * 64 + (((q) ^ (rc & 7)) * 8)];\
        bfr[ni][1] = *(const bf16x8*)&(BSB)[rc * 64 + (((4 + q) ^ (rc & 7)) * 8)];\
      }                                                                       \
    }                                                                         \
    bf16x8 afq[2][2];                                                         \
    _Pragma("unroll") for (int m2 = 0; m2 < 2; ++m2) {                        \
      int r = wrow * 128 + ((Q) * 2 + m2) * 16 + l16;                         \
      afq[m2][0] = *(const bf16x8*)&(ASB)[r * 64 + (((q) ^ (r & 7)) * 8)];    \
      afq[m2][1] = *(const bf16x8*)&(ASB)[r * 64 + (((4 + q) ^ (r & 7)) * 8)];\
    }                                                                         \
    STAGE_STMT;                                                               \
    VM_STMT;                                                                  \
    __builtin_amdgcn_s_barrier();                                             \
    asm volatile("s_waitcnt lgkmcnt(0)" ::: "memory");                        \
    __builtin_amdgcn_s_setprio(1);                                            \
    _Pragma("unroll") for (int s = 0; s < 2; ++s)                             \
      _Pragma("unroll") for (int m2 = 0; m2 < 2; ++m2)                        \
        _Pragma("unroll") for (int ni = 0; ni < 4; ++ni)                      \
          acc[(Q) * 2 + m2][ni] = __builtin_amdgcn_mfma_f32_16x16x32_bf16(    \
              afq[m2][s], bfr[ni][s], acc[(Q) * 2 + m2][ni], 0, 0, 0);        \
    __builtin_amdgcn_s_setprio(0);                                            \
    __builtin_amdgcn_s_barrier();                                             \
  }

// ---------- gemm256 (R18: 8-phase counted-vmcnt pipeline) -----------------
// C_z[M,N] = epi(A_z[M,K] @ BT_z[N,K]^T). 256x256 block, 512 thr = 8 waves
// (2 row x 4 col), wave 128x64 (acc[8][4]), BK=64, XOR-swizzled LDS,
// buf0 <-> even K-tiles, buf1 <-> odd K-tiles (64 KiB each, 128 KiB total).
__global__ __launch_bounds__(512) void gemm256(
    const bf16* __restrict__ A,
    const bf16* __restrict__ BT,
    bf16* __restrict__ C,
    int K, int N,
    long long batchA, long long batchB, long long batchC,
    const float* __restrict__ scale, const float* __restrict__ offset,
    int lrelu,
    const float* __restrict__ fuseW, float* __restrict__ facc,
    long long faccStride)
{
    __shared__ bf16 As[2 * 256 * 64];   // 64 KiB (buf0|buf1)
    __shared__ bf16 Bs[2 * 256 * 64];   // 64 KiB (buf0|buf1)
    const int tid  = threadIdx.x;
    const int lane = tid & 63;
    const int wave = tid >> 6;
    const int wrow = wave >> 2, wcol = wave & 3;
    const int q = lane >> 4, l16 = lane & 15;
    const int z = blockIdx.z;

    // XCD-aware bijective swizzle (x fastest in dispatch order).
    int bx = blockIdx.x, by = blockIdx.y;
    {
        int nwg = gridDim.x * gridDim.y;
        if (gridDim.z == 1 && (nwg & 7) == 0) {
            int lin = by * gridDim.x + bx;
            int cpx = nwg >> 3;
            int s = (lin & 7) * cpx + (lin >> 3);
            bx = s % gridDim.x;
            by = s / gridDim.x;
        }
    }
    const int row0 = by * 256;
    const int col0 = bx * 256;

    const bf16* Ap = A + (size_t)z * (size_t)batchA;
    const bf16* Bp = BT + (size_t)z * (size_t)batchB;

    f32x4 acc[8][4];
#pragma unroll
    for (int mi = 0; mi < 8; ++mi)
#pragma unroll
        for (int ni = 0; ni < 4; ++ni)
#pragma unroll
            for (int e = 0; e < 4; ++e) acc[mi][ni][e] = 0.f;

    // stage one half-tile (rows h*128..h*128+127) = 2 async loads/thread
    auto stageA2 = [&](int kk, int buf, int h) {
#pragma unroll
        for (int tt = 0; tt < 2; ++tt) {
            int idx = (2 * h + tt) * 512 + tid;
            int r = idx >> 3, sch = idx & 7;
            int gch = sch ^ (r & 7);
            async_load16(Ap + (size_t)(row0 + r) * K + kk + gch * 8,
                         &As[buf * 16384 + idx * 8]);
        }
    };
    auto stageB2 = [&](int kk, int buf, int h) {
#pragma unroll
        for (int tt = 0; tt < 2; ++tt) {
            int idx = (2 * h + tt) * 512 + tid;
            int r = idx >> 3, sch = idx & 7;
            int gch = sch ^ (r & 7);
            async_load16(Bp + (size_t)(col0 + r) * K + kk + gch * 8,
                         &Bs[buf * 16384 + idx * 8]);
        }
    };

    // prologue: tile0 (A+B) -> buf0, tile1 B -> buf1  (6 halves, 12 loads)
    stageA2(0, 0, 0); stageA2(0, 0, 1);
    stageB2(0, 0, 0); stageB2(0, 0, 1);
    stageB2(64, 1, 0); stageB2(64, 1, 1);
    // wait buf0's 8 loads (oldest); buf1.B's 4 stay in flight
    asm volatile("s_waitcnt vmcnt(4)" ::: "memory");
    __builtin_amdgcn_s_barrier();

    bf16x8 bfr[4][2];
    const bf16* A0 = As;          const bf16* B0 = Bs;
    const bf16* A1 = As + 16384;  const bf16* B1 = Bs + 16384;
    const int nt = K >> 6;        // even for all call sites (16 or 4)
    for (int i2 = 0; i2 < nt; i2 += 2) {
        const int kk1 = (i2 + 1) << 6, kk2 = (i2 + 2) << 6,
                  kk3 = (i2 + 3) << 6;
        const bool more = (i2 + 2) < nt;   // tiles i2+2 AND i2+3 exist
        // ---- tile i2 from buf0 (phases 1-4) ----
        PHASE(A0, B0, 0, true,  { stageA2(kk1, 1, 0); }, {});
        PHASE(A0, B0, 1, false, { stageA2(kk1, 1, 1); }, {});
        PHASE(A0, B0, 2, false, { if (more) stageB2(kk2, 0, 0); }, {});
        PHASE(A0, B0, 3, false, { if (more) stageB2(kk2, 0, 1); },
              { if (more)
                    asm volatile("s_waitcnt vmcnt(4)" ::: "memory");
                else
                    asm volatile("s_waitcnt vmcnt(0)" ::: "memory"); });
        // ---- tile i2+1 from buf1 (phases 5-8) ----
        PHASE(A1, B1, 0, true,  { if (more) stageA2(kk2, 0, 0); }, {});
        PHASE(A1, B1, 1, false, { if (more) stageA2(kk2, 0, 1); }, {});
        PHASE(A1, B1, 2, false, { if (more) stageB2(kk3, 1, 0); }, {});
        PHASE(A1, B1, 3, false, { if (more) stageB2(kk3, 1, 1); },
              { if (more)
                    asm volatile("s_waitcnt vmcnt(4)" ::: "memory"); });
    }

    // C/D layout (m89-verified): col = lane&15, row = (lane>>4)*4 + reg
    if (fuseW) {
#pragma unroll
        for (int mi = 0; mi < 8; ++mi)
#pragma unroll
            for (int i = 0; i < 4; ++i) {
                float rs = 0.f;
#pragma unroll
                for (int ni = 0; ni < 4; ++ni) {
                    int cc = col0 + wcol * 64 + ni * 16 + l16;
                    float val = acc[mi][ni][i] * scale[cc] + offset[cc];
                    val = val > 0.f ? val : 0.1f * val;
                    rs += val * fuseW[cc];
                }
                rs += __shfl_xor(rs, 1, 64);
                rs += __shfl_xor(rs, 2, 64);
                rs += __shfl_xor(rs, 4, 64);
                rs += __shfl_xor(rs, 8, 64);
                if (l16 == 0) {
                    int r = row0 + wrow * 128 + mi * 16 + q * 4 + i;
                    atomicAdd(facc + (size_t)z * faccStride + r, rs);
                }
            }
        return;
    }
    bf16* Cp = C + (size_t)z * (size_t)batchC;
#pragma unroll
    for (int mi = 0; mi < 8; ++mi)
#pragma unroll
        for (int ni = 0; ni < 4; ++ni)
#pragma unroll
            for (int i = 0; i < 4; ++i) {
                int r = row0 + wrow * 128 + mi * 16 + q * 4 + i;
                int cc = col0 + wcol * 64 + ni * 16 + l16;
                float val = acc[mi][ni][i];
                if (scale) val = val * scale[cc] + offset[cc];
                if (lrelu) val = val > 0.f ? val : 0.1f * val;
                Cp[(size_t)r * N + cc] = (bf16)val;
            }
}

// ---------- gemm_aff (R12-verified): symmetric affinity, 256x128, BK=64 ----
__global__ __launch_bounds__(512) void gemm_aff(
    const float* __restrict__ pairX,
    const float* __restrict__ ps, const float* __restrict__ po,
    const bf16* __restrict__ BT,
    int K,
    const float* __restrict__ scale, const float* __restrict__ offset,
    const float* __restrict__ sclW, float* __restrict__ w_acc)
{
    __shared__ bf16 As[256 * 64];   // 32 KiB
    __shared__ bf16 Bs[128 * 64];   // 16 KiB
    const int tid  = threadIdx.x;
    const int lane = tid & 63;
    const int wave = tid >> 6;
    const int wrow = wave >> 1, wcol = wave & 1;
    const int q = lane >> 4, l16 = lane & 15;
    const int col0 = blockIdx.x * 128;

    int ta = 0, rem = blockIdx.y;
    while (rem >= 16 - ta) { rem -= 16 - ta; ++ta; }
    const int tb = ta + rem;

    f32x4 acc[4][4];
#pragma unroll
    for (int mi = 0; mi < 4; ++mi)
#pragma unroll
        for (int ni = 0; ni < 4; ++ni)
#pragma unroll
            for (int e = 0; e < 4; ++e) acc[mi][ni][e] = 0.f;

    for (int kk = 0; kk < K; kk += 64) {
#pragma unroll
        for (int t = 0; t < 4; ++t) {
            int c = tid + t * 512;          // 2048 tasks: r=c>>3, ch=c&7
            int r = c >> 3, ch = c & 7;
            int g1 = ta * 16 + (r >> 4), g2 = tb * 16 + (r & 15);
            const float* xp = pairX + (size_t)g1 * K + kk + ch * 8;
            const float* yp = pairX + (size_t)g2 * K + kk + ch * 8;
            f32x4 x0 = *(const f32x4*)xp, x1 = *(const f32x4*)(xp + 4);
            f32x4 y0 = *(const f32x4*)yp, y1 = *(const f32x4*)(yp + 4);
            f32x4 sa = *(const f32x4*)(ps + kk + ch * 8);
            f32x4 sb = *(const f32x4*)(ps + kk + ch * 8 + 4);
            f32x4 oa = *(const f32x4*)(po + kk + ch * 8);
            f32x4 ob = *(const f32x4*)(po + kk + ch * 8 + 4);
            bf16x8 dv;
#pragma unroll
            for (int j = 0; j < 4; ++j) {
                float d0 = x0[j] - y0[j];
                float d1 = x1[j] - y1[j];
                dv[j]     = (bf16)(d0 * d0 * sa[j] + oa[j]);
                dv[j + 4] = (bf16)(d1 * d1 * sb[j] + ob[j]);
            }
            *(bf16x8*)&As[r * 64 + ((ch ^ (r & 7)) * 8)] = dv;
        }
#pragma unroll
        for (int t = 0; t < 2; ++t) {
            int idx = t * 512 + tid;        // 1024 chunks
            int r = idx >> 3, sch = idx & 7;
            int gch = sch ^ (r & 7);
            async_load16(BT + (size_t)(col0 + r) * K + kk + gch * 8,
                         &Bs[idx * 8]);
        }
        __syncthreads();

#pragma unroll
        for (int s = 0; s < 2; ++s) {
            bf16x8 af[4], bfr[4];
#pragma unroll
            for (int mi = 0; mi < 4; ++mi) {
                int r = wrow * 64 + mi * 16 + l16;
                af[mi] = *(const bf16x8*)&As[r * 64 + (((s * 4 + q) ^ (r & 7)) * 8)];
            }
#pragma unroll
            for (int ni = 0; ni < 4; ++ni) {
                int rc = wcol * 64 + ni * 16 + l16;
                bfr[ni] = *(const bf16x8*)&Bs[rc * 64 + (((s * 4 + q) ^ (rc & 7)) * 8)];
            }
#pragma unroll
            for (int mi = 0; mi < 4; ++mi)
#pragma unroll
                for (int ni = 0; ni < 4; ++ni)
                    acc[mi][ni] = __builtin_amdgcn_mfma_f32_16x16x32_bf16(
                        af[mi], bfr[ni], acc[mi][ni], 0, 0, 0);
        }
        __syncthreads();
    }

#pragma unroll
    for (int mi = 0; mi < 4; ++mi)
#pragma unroll
        for (int i = 0; i < 4; ++i) {
            float rs = 0.f;
#pragma unroll
            for (int ni = 0; ni < 4; ++ni) {
                int cc = col0 + wcol * 64 + ni * 16 + l16;
                float val = acc[mi][ni][i] * scale[cc] + offset[cc];
                val = val > 0.f ? val : 0.1f * val;
                rs += val * sclW[cc];
            }
            rs += __shfl_xor(rs, 1, 64);
            rs += __shfl_xor(rs, 2, 64);
            rs += __shfl_xor(rs, 4, 64);
            rs += __shfl_xor(rs, 8, 64);
            if (l16 == 0) {
                int r = wrow * 64 + mi * 16 + q * 4 + i;
                int g1 = ta * 16 + (r >> 4), g2 = tb * 16 + (r & 15);
                atomicAdd(w_acc + g1 * 256 + g2, rs);
            }
        }
}

extern "C" void kernel_launch(void* const* d_in, const int* in_sizes, int n_in,
                              void* d_out, int out_size, void* d_ws, size_t ws_size,
                              hipStream_t stream)
{
    const float* f_p   = (const float*)d_in[0];
    const float* f_g   = (const float*)d_in[1];
    const float* bn_g  = (const float*)d_in[2];
    const float* bn_b  = (const float*)d_in[3];
    const float* bn_m  = (const float*)d_in[4];
    const float* bn_v  = (const float*)d_in[5];
    const float* rf_W1 = (const float*)d_in[6];
    const float* rf_b1 = (const float*)d_in[7];
    const float* rf1_g = (const float*)d_in[8];
    const float* rf1_b = (const float*)d_in[9];
    const float* rf1_m = (const float*)d_in[10];
    const float* rf1_v = (const float*)d_in[11];
    const float* rf_W2 = (const float*)d_in[12];
    const float* rf_b2 = (const float*)d_in[13];
    const float* rf2_g = (const float*)d_in[14];
    const float* rf2_b = (const float*)d_in[15];
    const float* rf2_m = (const float*)d_in[16];
    const float* rf2_v = (const float*)d_in[17];
    const float* sfc_W = (const float*)d_in[18];
    const float* sfc_b = (const float*)d_in[19];
    const float* sbn_g = (const float*)d_in[20];
    const float* sbn_b = (const float*)d_in[21];
    const float* sbn_m = (const float*)d_in[22];
    const float* sbn_v = (const float*)d_in[23];
    const float* scl_W = (const float*)d_in[24];
    const float* scl_b = (const float*)d_in[25];
    const float* ffc_W = (const float*)d_in[26];
    const float* ffc_b = (const float*)d_in[27];
    const float* fbn_g = (const float*)d_in[28];
    const float* fbn_b = (const float*)d_in[29];
    const float* fbn_m = (const float*)d_in[30];
    const float* fbn_v = (const float*)d_in[31];
    const float* cls_W = (const float*)d_in[32];
    const float* cls_b = (const float*)d_in[33];

    const size_t MB = 1ull << 20;
    char* ws = (char*)d_ws;
    float* SC      = (float*)(ws);
    float *s0 = SC,        *o0 = SC + 1024;
    float *s1 = SC + 2048, *o1 = SC + 3072;
    float *s2 = SC + 4096, *o2 = SC + 5120;
    float *s3 = SC + 6144, *o3 = SC + 6656;
    float *s4 = SC + 7168, *o4 = SC + 7680;
    float* w_acc   = (float*)(ws + 65536);       // 256 KiB
    float* out_acc = (float*)(ws + 327680);      // 128 KiB
    bf16* wT       = (bf16*)(ws + 458752);       // 128 KiB
    bf16* W1T      = (bf16*)(ws + 1 * MB);
    bf16* W2T      = (bf16*)(ws + 3 * MB);
    bf16* sfcT     = (bf16*)(ws + 5 * MB);
    bf16* ffcT     = (bf16*)(ws + 6 * MB);

    int nc;
    if      (ws_size >= 170 * MB) nc = 1;        // confirmed since R3
    else if (ws_size >= 90 * MB)  nc = 2;
    else                          nc = 4;
    const int pc = 128 / nc;
    const int R  = pc * 256;
    const size_t hbytes = (size_t)R * 1024 * 2;
    bf16* bufA = (bf16*)(ws + 8 * MB);                    // h
    bf16* bufB = (bf16*)(ws + 8 * MB + hbytes);           // d, then t
    bf16* bufC = (bf16*)(ws + 8 * MB + 2 * hbytes);       // uT [pc][512][256]

    // 1. BN folds
    prep_kernel<<<dim3(4), 256, 0, stream>>>(bn_g, bn_b, bn_m, bn_v, nullptr, s0, o0, 1024);
    prep_kernel<<<dim3(4), 256, 0, stream>>>(rf1_g, rf1_b, rf1_m, rf1_v, rf_b1, s1, o1, 1024);
    prep_kernel<<<dim3(4), 256, 0, stream>>>(rf2_g, rf2_b, rf2_m, rf2_v, rf_b2, s2, o2, 1024);
    prep_kernel<<<dim3(2), 256, 0, stream>>>(sbn_g, sbn_b, sbn_m, sbn_v, sfc_b, s3, o3, 512);
    prep_kernel<<<dim3(2), 256, 0, stream>>>(fbn_g, fbn_b, fbn_m, fbn_v, ffc_b, s4, o4, 512);

    // 2. weight transposes (f32 -> bf16)
    wtrans_kernel<<<dim3(4, 1024), 256, 0, stream>>>(rf_W1, W1T, 1024, 1024);
    wtrans_kernel<<<dim3(4, 1024), 256, 0, stream>>>(rf_W2, W2T, 1024, 1024);
    wtrans_kernel<<<dim3(4, 512), 256, 0, stream>>>(sfc_W, sfcT, 1024, 512);
    wtrans_kernel<<<dim3(4, 512), 256, 0, stream>>>(ffc_W, ffcT, 1024, 512);

    // 3. zero accumulators (w_acc + out_acc contiguous)
    hipMemsetAsync(ws + 65536, 0, 393216, stream);

    // 4. symmetric affinity (R12-verified): grid (4,136)
    gemm_aff<<<dim3(4, 136), 512, 0, stream>>>(
        f_g, s0, o0, sfcT, 1024, s3, o3, scl_W, w_acc);
    // 5. wT[g2][g1] = bf16(w[canon] + scl_b)
    wconv_kernel<<<dim3(256), 256, 0, stream>>>(w_acc, scl_b, wT);

    // 6. probe chunks (all gemms 8-phase; d precomputed into bufB)
    for (int ci = 0; ci < nc; ++ci) {
        // d = bn1((f_p - f_g)^2)        [R,1024] bf16 -> bufB (dead after h)
        dprep_kernel<<<dim3(R / 2), 256, 0, stream>>>(
            f_p, f_g, s0, o0, bufB, ci * R);
        // h = lrelu(rf1(d @ W1 + b1))   [R,1024]
        gemm256<<<dim3(4, R / 256), 512, 0, stream>>>(
            bufB, W1T, bufA, 1024, 1024,
            0, 0, 0, s1, o1, 1, nullptr, nullptr, 0);
        // t = lrelu(rf2(h @ W2 + b2))   [R,1024] (overwrites d: dead)
        gemm256<<<dim3(4, R / 256), 512, 0, stream>>>(
            bufA, W2T, bufB, 1024, 1024,
            0, 0, 0, s2, o2, 1, nullptr, nullptr, 0);
        // uT_p = ffcT @ t_p^T           [pc][512][256]  (batched)
        gemm256<<<dim3(1, 2, pc), 512, 0, stream>>>(
            ffcT, bufB, bufC, 1024, 256,
            0, (long long)256 * 1024, (long long)512 * 256,
            nullptr, nullptr, 0, nullptr, nullptr, 0);
        // feat_p = lrelu(fbn(wT @ uT_p^T + b)) . cls_W -> out_acc  (batched)
        gemm256<<<dim3(2, 1, pc), 512, 0, stream>>>(
            wT, bufC, nullptr, 256, 512,
            0, (long long)512 * 256, 0,
            s4, o4, 1, cls_W, out_acc + (size_t)ci * pc * 256, 256);
    }
    // 7. d_out = out_acc + cls_b
    finout_kernel<<<dim3(128), 256, 0, stream>>>(out_acc, cls_b, (float*)d_out);
}